// Round 7
// baseline (840.283 us; speedup 1.0000x reference)
//
#include <hip/hip_runtime.h>
#include <hip/hip_bf16.h>

#define SS 256
#define BB 512
#define II 64
#define HH 128
#define DD 32

typedef __attribute__((ext_vector_type(8))) short short8;   // 8 bf16 (4 VGPRs)
typedef __attribute__((ext_vector_type(4))) float f32x4;

__device__ __forceinline__ short f2bf(float f) {
    unsigned u = __builtin_bit_cast(unsigned, f);
    u += 0x7FFFu + ((u >> 16) & 1u);            // RNE
    return (short)(u >> 16);
}
__device__ __forceinline__ int pack2bf(float a, float b) {
    return (int)((((unsigned)(unsigned short)f2bf(b)) << 16) |
                  ((unsigned)(unsigned short)f2bf(a)));
}
__device__ __forceinline__ short8 load8bf(const float* p) {
    short8 r;
#pragma unroll
    for (int j = 0; j < 8; ++j) r[j] = f2bf(p[j]);
    return r;
}

// barrier with LDS-only drain: global stores/prefetches stay in flight
__device__ __forceinline__ void sync_lds() {
    __builtin_amdgcn_s_waitcnt(0xc07f);   // lgkmcnt(0); vmcnt/expcnt = max
    __builtin_amdgcn_s_barrier();
}

// ---------------------------------------------------------------------------
// K1: masked per-channel sum/sumsq for BOTH x (C=64) and x_d (C=32).
// blocks [0,256) -> x, [256,384) -> x_d.
// acc layout: [0:64]=sum_x [64:128]=sq_x [128:160]=sum_d [160:192]=sq_d
// ---------------------------------------------------------------------------
__global__ __launch_bounds__(256) void stats_kernel(
    const float* __restrict__ x, const float* __restrict__ xd,
    const int* __restrict__ lengths, double* __restrict__ acc)
{
    __shared__ float red_s[256];
    __shared__ float red_q[256];
    const int rows = SS * BB;
    int blk = blockIdx.x;
    const float* v;
    int C, rpb, base;
    if (blk < 256) { v = x;  C = II; rpb = rows / 256; base = 0; }
    else           { v = xd; C = DD; rpb = rows / 128; base = 128; blk -= 256; }

    const int tid = threadIdx.x;
    const int c   = tid & (C - 1);
    const int rg  = tid / C;
    const int rpg = 256 / C;
    const int r0  = blk * rpb;
    const int r1  = r0 + rpb;
    float s = 0.f, q = 0.f;
    for (int r = r0 + rg; r < r1; r += rpg) {
        const int b  = r & (BB - 1);
        const int si = r >> 9;
        if (si < lengths[b]) {
            const float xv = v[(size_t)r * C + c];
            s += xv;
            q  = fmaf(xv, xv, q);
        }
    }
    red_s[tid] = s; red_q[tid] = q;
    __syncthreads();
    if (rg == 0) {
        for (int g = 1; g < rpg; ++g) { s += red_s[c + g * C]; q += red_q[c + g * C]; }
        atomicAdd(&acc[base + c],     (double)s);
        atomicAdd(&acc[base + C + c], (double)q);
    }
}

// ---------------------------------------------------------------------------
// K2: finalize -> folded BN coefficients  xn = x*a + c
// der layout: [0:64]=a_x [64:128]=c_x [128:160]=a_d [160:192]=c_d
// ---------------------------------------------------------------------------
__global__ __launch_bounds__(128) void finalize_kernel(
    const int* __restrict__ lengths, const double* __restrict__ acc,
    const float* __restrict__ bn_g, const float* __restrict__ bn_b,
    const float* __restrict__ bnd_g, const float* __restrict__ bnd_b,
    float* __restrict__ der)
{
    __shared__ int redc[128];
    __shared__ double s_inv;
    const int tid = threadIdx.x;
    int cs = 0;
    for (int i = tid; i < BB; i += 128) cs += lengths[i];
    redc[tid] = cs;
    __syncthreads();
    if (tid == 0) {
        int tot = 0;
        for (int i = 0; i < 128; ++i) tot += redc[i];
        s_inv = 1.0 / (double)tot;
    }
    __syncthreads();
    const double inv = s_inv;
    if (tid < 64) {
        const double mu  = acc[tid] * inv;
        const double var = acc[64 + tid] * inv - mu * mu;
        const float  rs  = rsqrtf((float)(var + 1e-5));
        const float  a   = rs * bn_g[tid];
        der[tid]      = a;
        der[64 + tid] = bn_b[tid] - (float)mu * a;
    } else if (tid < 96) {
        const int i = tid - 64;
        const double mu  = acc[128 + i] * inv;
        const double var = acc[160 + i] * inv - mu * mu;
        const float  rs  = rsqrtf((float)(var + 1e-5));
        const float  a   = rs * bnd_g[i];
        der[128 + i] = a;
        der[160 + i] = bnd_b[i] - (float)mu * a;
    }
}

// ---------------------------------------------------------------------------
// K3: GRU. 16 blocks x 512 threads; block = 32 batch rows as TWO 16-token
// groups. Wave w: group g=w>>2, unit-range ws3=w&3 (32 units = 2 M-tiles).
// LDS B-frag reads (h,xn) are per-group: 4 waves share them instead of 8 ->
// per-batch-row LDS cost halves vs the 16-row block. Weights VGPR-resident
// (36 frag-sets). ONE lgkm-only barrier per step. y written as bf16 to the
// workspace (use_ws=1) or f32 to out (fallback).
// ---------------------------------------------------------------------------
__global__ __launch_bounds__(512, 2) void gru_kernel(
    const float* __restrict__ x, const int* __restrict__ lengths,
    const float* __restrict__ Wih, const float* __restrict__ Whh,
    const float* __restrict__ bih, const float* __restrict__ bhh,
    const float* __restrict__ der,
    short* __restrict__ ybf, float* __restrict__ yf32,
    float* __restrict__ hlast, int use_ws)
{
    __shared__ __align__(16) short hbf[2][2][16 * 136];
    __shared__ __align__(16) short xbf[2][2][16 * 72];

    const int tid  = threadIdx.x;
    const int w    = tid >> 6;
    const int l    = tid & 63;
    const int col  = l & 15;       // token within group
    const int quad = l >> 4;
    const int g    = w >> 2;       // token group 0/1
    const int ws3  = w & 3;        // unit range [32*ws3, 32*ws3+32)
    const int b0   = blockIdx.x * 32;
    const int tokb = b0 + 16 * g + col;          // this lane's batch row

    // ---- weight A-fragments, 2 M-tiles per gate (persistent in VGPRs) ----
    short8 WR[2][6], WZ[2][6], WNh[2][4], WNx[2][2];
#pragma unroll
    for (int mt = 0; mt < 2; ++mt) {
        const int ur = 32 * ws3 + 16 * mt + col;
#pragma unroll
        for (int ks = 0; ks < 4; ++ks) {
            const int ko = ks * 32 + quad * 8;
            WR[mt][ks]  = load8bf(&Whh[(size_t)ur * HH + ko]);
            WZ[mt][ks]  = load8bf(&Whh[(size_t)(HH + ur) * HH + ko]);
            WNh[mt][ks] = load8bf(&Whh[(size_t)(2 * HH + ur) * HH + ko]);
        }
#pragma unroll
        for (int ks = 0; ks < 2; ++ks) {
            const int ko = ks * 32 + quad * 8;
            WR[mt][4 + ks] = load8bf(&Wih[(size_t)ur * II + ko]);
            WZ[mt][4 + ks] = load8bf(&Wih[(size_t)(HH + ur) * II + ko]);
            WNx[mt][ks]    = load8bf(&Wih[(size_t)(2 * HH + ur) * II + ko]);
        }
    }
    float br_[2][4], bz_[2][4], bnh_[2][4], bnx_[2][4];
#pragma unroll
    for (int mt = 0; mt < 2; ++mt)
#pragma unroll
        for (int r = 0; r < 4; ++r) {
            const int gg = 32 * ws3 + 16 * mt + 4 * quad + r;
            br_[mt][r]  = bih[gg] + bhh[gg];
            bz_[mt][r]  = bih[HH + gg] + bhh[HH + gg];
            bnh_[mt][r] = bhh[2 * HH + gg];
            bnx_[mt][r] = bih[2 * HH + gg];
        }
    const int len = lengths[tokb];

    // x staging: 512 threads x float4 covers 32 rows x 64 cols
    const int srow = tid >> 4, scol = (tid & 15) * 4;
    const float4 a4 = *(const float4*)&der[scol];
    const float4 c4 = *(const float4*)&der[64 + scol];

    for (int i = tid; i < 2 * 16 * 136 / 2; i += 512) ((int*)hbf[0])[i] = 0;
    float hreg[2][4] = {{0.f,0.f,0.f,0.f},{0.f,0.f,0.f,0.f}};
    {
        const float4 xv = *(const float4*)&x[(size_t)(b0 + srow) * II + scol];
        int2 pk;
        pk.x = pack2bf(fmaf(xv.x, a4.x, c4.x), fmaf(xv.y, a4.y, c4.y));
        pk.y = pack2bf(fmaf(xv.z, a4.z, c4.z), fmaf(xv.w, a4.w, c4.w));
        *(int2*)&xbf[0][srow >> 4][(srow & 15) * 72 + scol] = pk;
    }
    sync_lds();

    int p = 0;
    for (int t = 0; t < SS; ++t) {
        float4 xv;
        if (t + 1 < SS)
            xv = *(const float4*)&x[(size_t)((t + 1) * BB + b0 + srow) * II + scol];

        // shared B-fragments for this wave's token group
        short8 Hf[4];
#pragma unroll
        for (int ks = 0; ks < 4; ++ks)
            Hf[ks] = *(const short8*)&hbf[p][g][col * 136 + ks * 32 + quad * 8];
        const short8 XN0 = *(const short8*)&xbf[p][g][col * 72 + quad * 8];
        const short8 XN1 = *(const short8*)&xbf[p][g][col * 72 + 32 + quad * 8];

        f32x4 ar[2], az[2], anh[2], anx[2];
#pragma unroll
        for (int mt = 0; mt < 2; ++mt) {
            ar[mt]  = (f32x4){br_[mt][0],  br_[mt][1],  br_[mt][2],  br_[mt][3]};
            az[mt]  = (f32x4){bz_[mt][0],  bz_[mt][1],  bz_[mt][2],  bz_[mt][3]};
            anh[mt] = (f32x4){bnh_[mt][0], bnh_[mt][1], bnh_[mt][2], bnh_[mt][3]};
            anx[mt] = (f32x4){bnx_[mt][0], bnx_[mt][1], bnx_[mt][2], bnx_[mt][3]};
#pragma unroll
            for (int ks = 0; ks < 4; ++ks) {
                ar[mt]  = __builtin_amdgcn_mfma_f32_16x16x32_bf16(WR[mt][ks],  Hf[ks], ar[mt],  0, 0, 0);
                az[mt]  = __builtin_amdgcn_mfma_f32_16x16x32_bf16(WZ[mt][ks],  Hf[ks], az[mt],  0, 0, 0);
                anh[mt] = __builtin_amdgcn_mfma_f32_16x16x32_bf16(WNh[mt][ks], Hf[ks], anh[mt], 0, 0, 0);
            }
            ar[mt]  = __builtin_amdgcn_mfma_f32_16x16x32_bf16(WR[mt][4],  XN0, ar[mt],  0, 0, 0);
            ar[mt]  = __builtin_amdgcn_mfma_f32_16x16x32_bf16(WR[mt][5],  XN1, ar[mt],  0, 0, 0);
            az[mt]  = __builtin_amdgcn_mfma_f32_16x16x32_bf16(WZ[mt][4],  XN0, az[mt],  0, 0, 0);
            az[mt]  = __builtin_amdgcn_mfma_f32_16x16x32_bf16(WZ[mt][5],  XN1, az[mt],  0, 0, 0);
            anx[mt] = __builtin_amdgcn_mfma_f32_16x16x32_bf16(WNx[mt][0], XN0, anx[mt], 0, 0, 0);
            anx[mt] = __builtin_amdgcn_mfma_f32_16x16x32_bf16(WNx[mt][1], XN1, anx[mt], 0, 0, 0);
        }

        const bool valid = (t < len);
#pragma unroll
        for (int mt = 0; mt < 2; ++mt) {
#pragma unroll
            for (int r = 0; r < 4; ++r) {
                const float rg = __builtin_amdgcn_rcpf(1.f + __expf(-ar[mt][r]));
                const float zg = __builtin_amdgcn_rcpf(1.f + __expf(-az[mt][r]));
                const float nv = anx[mt][r] + rg * anh[mt][r];
                const float ng = 1.f - 2.f * __builtin_amdgcn_rcpf(1.f + __expf(2.f * nv));
                const float hnew = (1.f - zg) * ng + zg * hreg[mt][r];
                hreg[mt][r] = valid ? hnew : hreg[mt][r];
            }
            int2 pk;
            pk.x = pack2bf(hreg[mt][0], hreg[mt][1]);
            pk.y = pack2bf(hreg[mt][2], hreg[mt][3]);
            *(int2*)&hbf[p ^ 1][g][col * 136 + 32 * ws3 + 16 * mt + 4 * quad] = pk;
            // y store (drain-free)
            if (use_ws) {
                *(int2*)&ybf[(((size_t)t * BB + tokb) << 7) + 32 * ws3 + 16 * mt + 4 * quad] = pk;
            } else {
                float4 o;
                o.x = hreg[mt][0]; o.y = hreg[mt][1]; o.z = hreg[mt][2]; o.w = hreg[mt][3];
                *(float4*)&yf32[(((size_t)t * BB + tokb) << 7) + 32 * ws3 + 16 * mt + 4 * quad] = o;
            }
        }
        if (t + 1 < SS) {
            int2 pk;
            pk.x = pack2bf(fmaf(xv.x, a4.x, c4.x), fmaf(xv.y, a4.y, c4.y));
            pk.y = pack2bf(fmaf(xv.z, a4.z, c4.z), fmaf(xv.w, a4.w, c4.w));
            *(int2*)&xbf[p ^ 1][srow >> 4][(srow & 15) * 72 + scol] = pk;
        }
        sync_lds();
        p ^= 1;
    }

#pragma unroll
    for (int mt = 0; mt < 2; ++mt) {
        float4 hl;
        hl.x = hreg[mt][0]; hl.y = hreg[mt][1];
        hl.z = hreg[mt][2]; hl.w = hreg[mt][3];
        *(float4*)&hlast[((size_t)tokb << 7) + 32 * ws3 + 16 * mt + 4 * quad] = hl;
    }
}

// ---------------------------------------------------------------------------
// K4: 3-layer MLP. 1024 blocks x 512 threads; 8 tiles of 16 tokens per block,
// 3-stage pipeline (L1 i / L2 i-1 / L3 i-2), ONE lgkm-only barrier per step.
// y input read as bf16 from workspace (use_ws=1) or f32 from io (fallback).
// __launch_bounds__(512,4) caps VGPR at 128 -> 4 blocks/CU.
// ---------------------------------------------------------------------------
__global__ __launch_bounds__(512, 4) void mlp_kernel(
    const float* __restrict__ xd, const int* __restrict__ lengths,
    const float* __restrict__ W1, const float* __restrict__ b1v,
    const float* __restrict__ W2, const float* __restrict__ b2v,
    const float* __restrict__ W3, const float* __restrict__ b3v,
    const float* __restrict__ der, const short* __restrict__ ybf,
    float* io, int use_ws)
{
    __shared__ __align__(16) short z0[2][16 * 168];
    __shared__ __align__(16) short d1b[2][16 * 136];
    __shared__ __align__(16) short d2b[2][16 * 136];

    const int tid  = threadIdx.x;
    const int w    = tid >> 6;
    const int l    = tid & 63;
    const int col  = l & 15;
    const int quad = l >> 4;
    const int ur   = 16 * w + col;
    const int g0   = 16 * w + quad * 4;

    short8 F1[5], F2[4], F3[4];
#pragma unroll
    for (int ks = 0; ks < 5; ++ks)
        F1[ks] = load8bf(&W1[(size_t)ur * 160 + ks * 32 + quad * 8]);
#pragma unroll
    for (int ks = 0; ks < 4; ++ks) {
        const int ko = ks * 32 + quad * 8;
        F2[ks] = load8bf(&W2[(size_t)ur * HH + ko]);
        F3[ks] = load8bf(&W3[(size_t)ur * HH + ko]);
    }
    float bb1_[4], bb2_[4], bb3_[4];
#pragma unroll
    for (int r = 0; r < 4; ++r) {
        bb1_[r] = b1v[g0 + r]; bb2_[r] = b2v[g0 + r]; bb3_[r] = b3v[g0 + r];
    }

    // staging maps: y = 512 thr (16 rows x 128 cols); xd = 256 thr x float2
    const int yrow = tid >> 5, yc = (tid & 31) * 4;
    const int drow = tid >> 4, dcol = (tid & 15) * 2;
    float ad0 = 0.f, ad1 = 0.f, cd0 = 0.f, cd1 = 0.f;
    if (tid < 256) {
        ad0 = der[128 + dcol]; ad1 = der[128 + dcol + 1];
        cd0 = der[160 + dcol]; cd1 = der[160 + dcol + 1];
    }

    const int tile0 = blockIdx.x * 8;

    {   // pre-stage tile 0
        const size_t tok0 = (size_t)tile0 * 16;
        if (use_ws) {
            const int2 yv = *(const int2*)&ybf[((tok0 + yrow) << 7) + yc];
            *(int2*)&z0[0][yrow * 168 + yc] = yv;
        } else {
            const float4 yv = *(const float4*)&io[((tok0 + yrow) << 7) + yc];
            int2 pk; pk.x = pack2bf(yv.x, yv.y); pk.y = pack2bf(yv.z, yv.w);
            *(int2*)&z0[0][yrow * 168 + yc] = pk;
        }
        if (tid < 256) {
            const float2 dv = *(const float2*)&xd[(tok0 + drow) * DD + dcol];
            *(int*)&z0[0][drow * 168 + HH + dcol] =
                pack2bf(fmaf(dv.x, ad0, cd0), fmaf(dv.y, ad1, cd1));
        }
    }
    sync_lds();

    int p = 0;
    for (int it = 0; it <= 9; ++it) {
        // prefetch tile it+1
        int2 yvi; float4 yvf; float2 dv;
        const int nt = it + 1;
        if (nt <= 7) {
            const size_t tok0n = (size_t)(tile0 + nt) * 16;
            if (use_ws) yvi = *(const int2*)&ybf[((tok0n + yrow) << 7) + yc];
            else        yvf = *(const float4*)&io[((tok0n + yrow) << 7) + yc];
            if (tid < 256) dv = *(const float2*)&xd[(tok0n + drow) * DD + dcol];
        }

        // L1 (tile it): z0[p] -> d1b[p^1]
        f32x4 a1 = {bb1_[0], bb1_[1], bb1_[2], bb1_[3]};
#pragma unroll
        for (int ks = 0; ks < 5; ++ks)
            a1 = __builtin_amdgcn_mfma_f32_16x16x32_bf16(
                F1[ks], *(const short8*)&z0[p][col * 168 + ks * 32 + quad * 8], a1, 0, 0, 0);
        {
            int2 pk;
            pk.x = pack2bf(fmaxf(a1[0], 0.f), fmaxf(a1[1], 0.f));
            pk.y = pack2bf(fmaxf(a1[2], 0.f), fmaxf(a1[3], 0.f));
            *(int2*)&d1b[p ^ 1][col * 136 + g0] = pk;
        }

        // L2 (tile it-1): d1b[p] -> d2b[p^1]
        f32x4 a2 = {bb2_[0], bb2_[1], bb2_[2], bb2_[3]};
#pragma unroll
        for (int ks = 0; ks < 4; ++ks)
            a2 = __builtin_amdgcn_mfma_f32_16x16x32_bf16(
                F2[ks], *(const short8*)&d1b[p][col * 136 + ks * 32 + quad * 8], a2, 0, 0, 0);
        {
            int2 pk;
            pk.x = pack2bf(fmaxf(a2[0], 0.f), fmaxf(a2[1], 0.f));
            pk.y = pack2bf(fmaxf(a2[2], 0.f), fmaxf(a2[3], 0.f));
            *(int2*)&d2b[p ^ 1][col * 136 + g0] = pk;
        }

        // L3 (tile it-2): d2b[p] -> out (drain-free store)
        f32x4 a3 = {bb3_[0], bb3_[1], bb3_[2], bb3_[3]};
#pragma unroll
        for (int ks = 0; ks < 4; ++ks)
            a3 = __builtin_amdgcn_mfma_f32_16x16x32_bf16(
                F3[ks], *(const short8*)&d2b[p][col * 136 + ks * 32 + quad * 8], a3, 0, 0, 0);
        if (it >= 2) {
            const int tok0 = (tile0 + it - 2) * 16;
            const int tI = tok0 >> 9;
            const int bI = tok0 & (BB - 1);
            const bool v = tI < lengths[bI + col];
            float4 o;
            o.x = v ? fmaxf(a3[0], 0.f) : 0.f;
            o.y = v ? fmaxf(a3[1], 0.f) : 0.f;
            o.z = v ? fmaxf(a3[2], 0.f) : 0.f;
            o.w = v ? fmaxf(a3[3], 0.f) : 0.f;
            *(float4*)&io[(((size_t)tok0 + col) << 7) + g0] = o;
        }

        // commit prefetched tile
        if (nt <= 7) {
            if (use_ws) {
                *(int2*)&z0[p ^ 1][yrow * 168 + yc] = yvi;
            } else {
                int2 pk; pk.x = pack2bf(yvf.x, yvf.y); pk.y = pack2bf(yvf.z, yvf.w);
                *(int2*)&z0[p ^ 1][yrow * 168 + yc] = pk;
            }
            if (tid < 256)
                *(int*)&z0[p ^ 1][drow * 168 + HH + dcol] =
                    pack2bf(fmaf(dv.x, ad0, cd0), fmaf(dv.y, ad1, cd1));
        }
        sync_lds();
        p ^= 1;
    }
}

// ---------------------------------------------------------------------------
extern "C" void kernel_launch(void* const* d_in, const int* in_sizes, int n_in,
                              void* d_out, int out_size, void* d_ws, size_t ws_size,
                              hipStream_t stream)
{
    (void)in_sizes; (void)n_in; (void)out_size;
    const float* x     = (const float*)d_in[0];
    const float* xd    = (const float*)d_in[1];
    const int*   lens  = (const int*)d_in[2];
    const float* bn_g  = (const float*)d_in[3];
    const float* bn_b  = (const float*)d_in[4];
    const float* bnd_g = (const float*)d_in[5];
    const float* bnd_b = (const float*)d_in[6];
    const float* Wih   = (const float*)d_in[7];
    const float* Whh   = (const float*)d_in[8];
    const float* bih   = (const float*)d_in[9];
    const float* bhh   = (const float*)d_in[10];
    // d_in[11], d_in[12]: attn_W, attn_b — softmax over size-1 axis == identity
    const float* W1    = (const float*)d_in[13];
    const float* b1    = (const float*)d_in[14];
    const float* W2    = (const float*)d_in[15];
    const float* b2    = (const float*)d_in[16];
    const float* W3    = (const float*)d_in[17];
    const float* b3    = (const float*)d_in[18];

    float* out   = (float*)d_out;
    float* hlast = out + (size_t)SS * BB * HH;

    double* acc = (double*)d_ws;                       // 192 doubles
    float*  der = (float*)((char*)d_ws + 2048);        // 192 floats
    short*  ybf = (short*)((char*)d_ws + 4096);        // bf16 y: 33.6 MB

    const size_t need = 4096 + (size_t)SS * BB * HH * sizeof(short);
    const int use_ws = (ws_size >= need) ? 1 : 0;

    hipMemsetAsync(d_ws, 0, 2048, stream);

    stats_kernel<<<384, 256, 0, stream>>>(x, xd, lens, acc);
    finalize_kernel<<<1, 128, 0, stream>>>(lens, acc, bn_g, bn_b, bnd_g, bnd_b, der);

    gru_kernel<<<BB / 32, 512, 0, stream>>>(x, lens, Wih, Whh, bih, bhh, der,
                                            ybf, out, hlast, use_ws);

    mlp_kernel<<<1024, 512, 0, stream>>>(xd, lens, W1, b1, W2, b2, W3, b3,
                                         der, ybf, out, use_ws);
}